// Round 6
// baseline (241.127 us; speedup 1.0000x reference)
//
#include <hip/hip_runtime.h>
#include <stdint.h>

// SelfAttention: B=4, S=2048, D=1024, causal, single head of dim 1024.
// Inputs/outputs fp32 on device; GEMMs run bf16 MFMA with fp32 accumulation.
// R6: scores -> 128x256 tiles (288 blocks, single round); pv -> K-split
// jobs <=1024 units, longest-first, atomicAdd combine for split rows.

typedef unsigned short u16;
typedef __attribute__((ext_vector_type(8))) short shortx8;  // 8 bf16 (4 VGPRs)
typedef __attribute__((ext_vector_type(4))) float floatx4;

static constexpr int BB = 4;
static constexpr int SS = 2048;
static constexpr int DD = 1024;

__device__ __forceinline__ u16 f2bf(float f) {
  union { float f; uint32_t u; } c; c.f = f;
  uint32_t u = c.u;
  return (u16)((u + 0x7fffu + ((u >> 16) & 1u)) >> 16);  // RNE
}

__device__ __forceinline__ float bfhi2f(uint32_t u) {
  union { uint32_t u; float f; } c; c.u = u & 0xffff0000u; return c.f;
}
__device__ __forceinline__ float bflo2f(uint32_t u) {
  union { uint32_t u; float f; } c; c.u = u << 16; return c.f;
}

#define GLOAD_LDS16(g, l)                                                              \
  __builtin_amdgcn_global_load_lds((const __attribute__((address_space(1))) void*)(g), \
                                   (__attribute__((address_space(3))) void*)(l), 16, 0, 0)

// 128x128 C-tile GEMM core, BK=64, XOR-swizzled LDS (R5: zero bank conflicts).
//   logical 16B chunk c (0..7) of row r lives at physical chunk c ^ (r & 7).
__device__ __forceinline__ void gemm_core_128(
    const u16* __restrict__ A, const u16* __restrict__ Bt,
    int lda, int ldb, int m0, int n0, int kend, floatx4 acc[4][4])
{
  __shared__ u16 lA[128 * 64];
  __shared__ u16 lB[128 * 64];
  const int t = threadIdx.x;
  const int w = t >> 6, l = t & 63;
  const int wm = w >> 1, wn = w & 1;
  const int sr = l >> 3;
  const int scq = ((l & 7) ^ (l >> 3)) * 8;   // swizzled SOURCE chunk (elems)

#pragma unroll
  for (int i = 0; i < 4; ++i)
#pragma unroll
    for (int j = 0; j < 4; ++j)
      acc[i][j] = (floatx4){0.f, 0.f, 0.f, 0.f};

  const u16* Ab = A + (size_t)m0 * lda;
  const u16* Bb = Bt + (size_t)n0 * ldb;

  for (int k0 = 0; k0 < kend; k0 += 64) {
#pragma unroll
    for (int i = 0; i < 4; ++i) {
      const int row = w * 32 + i * 8;
      GLOAD_LDS16(Ab + (size_t)(row + sr) * lda + k0 + scq, &lA[row * 64]);
      GLOAD_LDS16(Bb + (size_t)(row + sr) * ldb + k0 + scq, &lB[row * 64]);
    }
    __syncthreads();

#pragma unroll
    for (int ks = 0; ks < 2; ++ks) {
      const int ca = ((ks * 4 + (l >> 4)) ^ (l & 7)) * 8;
      shortx8 af[4], bf[4];
#pragma unroll
      for (int i = 0; i < 4; ++i)
        af[i] = *(const shortx8*)&lA[(wm * 64 + i * 16 + (l & 15)) * 64 + ca];
#pragma unroll
      for (int i = 0; i < 4; ++i)
        bf[i] = *(const shortx8*)&lB[(wn * 64 + i * 16 + (l & 15)) * 64 + ca];
#pragma unroll
      for (int i = 0; i < 4; ++i)
#pragma unroll
        for (int j = 0; j < 4; ++j)
          acc[i][j] = __builtin_amdgcn_mfma_f32_16x16x32_bf16(af[i], bf[j], acc[i][j], 0, 0, 0);
    }
    __syncthreads();
  }
}

// 128x256 C-tile core (scores): waves 2x2, each wave 64 rows x 128 cols,
// acc[4][8]. Same BK=64 + XOR swizzle. LDS 16KB(A) + 32KB(B).
__device__ __forceinline__ void gemm_core_128x256(
    const u16* __restrict__ A, const u16* __restrict__ Bt,
    int lda, int ldb, int m0, int n0, int kend, floatx4 acc[4][8])
{
  __shared__ u16 lA[128 * 64];
  __shared__ u16 lB[256 * 64];
  const int t = threadIdx.x;
  const int w = t >> 6, l = t & 63;
  const int wm = w >> 1, wn = w & 1;
  const int sr = l >> 3;
  const int scq = ((l & 7) ^ (l >> 3)) * 8;

#pragma unroll
  for (int i = 0; i < 4; ++i)
#pragma unroll
    for (int j = 0; j < 8; ++j)
      acc[i][j] = (floatx4){0.f, 0.f, 0.f, 0.f};

  const u16* Ab = A + (size_t)m0 * lda;
  const u16* Bb = Bt + (size_t)n0 * ldb;

  for (int k0 = 0; k0 < kend; k0 += 64) {
#pragma unroll
    for (int i = 0; i < 4; ++i) {
      const int row = w * 32 + i * 8;
      GLOAD_LDS16(Ab + (size_t)(row + sr) * lda + k0 + scq, &lA[row * 64]);
    }
#pragma unroll
    for (int i = 0; i < 8; ++i) {
      const int row = w * 64 + i * 8;
      GLOAD_LDS16(Bb + (size_t)(row + sr) * ldb + k0 + scq, &lB[row * 64]);
    }
    __syncthreads();

#pragma unroll
    for (int ks = 0; ks < 2; ++ks) {
      const int ca = ((ks * 4 + (l >> 4)) ^ (l & 7)) * 8;
      shortx8 af[4], bf[8];
#pragma unroll
      for (int i = 0; i < 4; ++i)
        af[i] = *(const shortx8*)&lA[(wm * 64 + i * 16 + (l & 15)) * 64 + ca];
#pragma unroll
      for (int j = 0; j < 8; ++j)
        bf[j] = *(const shortx8*)&lB[(wn * 128 + j * 16 + (l & 15)) * 64 + ca];
#pragma unroll
      for (int i = 0; i < 4; ++i)
#pragma unroll
        for (int j = 0; j < 8; ++j)
          acc[i][j] = __builtin_amdgcn_mfma_f32_16x16x32_bf16(af[i], bf[j], acc[i][j], 0, 0, 0);
    }
    __syncthreads();
  }
}

// ---- kernel 0: prep = x_convert (blocks 0..8191) + wt_build (8192..8959) ----
__global__ __launch_bounds__(256) void prep(const float* __restrict__ x,
                                            const float* __restrict__ WQ,
                                            const float* __restrict__ WK,
                                            const float* __restrict__ WV,
                                            u16* __restrict__ xb,
                                            u16* __restrict__ Wt) {
  __shared__ float tile[64][65];
  const int bid = blockIdx.x;
  const int t = threadIdx.x;
  if (bid < 8192) {
    const size_t i = (size_t)bid * 256 + t;
    float4 v = ((const float4*)x)[i];
    ushort4 o;
    o.x = f2bf(v.x); o.y = f2bf(v.y); o.z = f2bf(v.z); o.w = f2bf(v.w);
    ((ushort4*)xb)[i] = o;
    return;
  }
  const int r = bid - 8192;
  const int wsel = r >> 8;
  const int rr = r & 255;
  const int k0 = (rr >> 4) * 64, n0 = (rr & 15) * 64;
  const float* W = wsel == 0 ? WQ : (wsel == 1 ? WK : WV);
  const int tx = t & 63, ty = t >> 6;
#pragma unroll
  for (int i = 0; i < 16; ++i)
    tile[ty + i * 4][tx] = W[(size_t)(k0 + ty + i * 4) * DD + n0 + tx];
  __syncthreads();
  u16* dst = Wt + (size_t)wsel * DD * DD;
#pragma unroll
  for (int i = 0; i < 16; ++i)
    dst[(size_t)(n0 + ty + i * 4) * DD + k0 + tx] = f2bf(tile[tx][ty + i * 4]);
}

// ---- kernel 1: fused QKV projection; V written transposed into Vt ----
__global__ __launch_bounds__(256, 2) void qkv_gemm(const u16* __restrict__ x,
                                                   const u16* __restrict__ Wt,
                                                   u16* __restrict__ Q,
                                                   u16* __restrict__ K,
                                                   u16* __restrict__ Vt) {
  const int m0 = blockIdx.x * 128;
  const int n0t = blockIdx.y * 128;
  floatx4 acc[4][4];
  gemm_core_128(x, Wt, DD, DD, m0, n0t, DD, acc);

  const int t = threadIdx.x, w = t >> 6, l = t & 63;
  const int wm = w >> 1, wn = w & 1;

  if (n0t >= 2048) {
    const int bb = m0 >> 11;
    const int s0 = (m0 & 2047) + wm * 64 + (l >> 4) * 4;
    u16* vt = Vt + (size_t)bb * DD * SS;
#pragma unroll
    for (int i = 0; i < 4; ++i)
#pragma unroll
      for (int j = 0; j < 4; ++j) {
        const int n = (n0t - 2048) + wn * 64 + j * 16 + (l & 15);
        const int s = s0 + i * 16;
        ushort4 o4;
        o4.x = f2bf(acc[i][j][0]);
        o4.y = f2bf(acc[i][j][1]);
        o4.z = f2bf(acc[i][j][2]);
        o4.w = f2bf(acc[i][j][3]);
        *(ushort4*)(vt + (size_t)n * SS + s) = o4;
      }
    return;
  }

  u16* out = (n0t < 1024) ? Q : K;
  const int n0 = n0t & 1023;
#pragma unroll
  for (int i = 0; i < 4; ++i)
#pragma unroll
    for (int j = 0; j < 4; ++j)
#pragma unroll
      for (int r = 0; r < 4; ++r) {
        const int m = m0 + wm * 64 + i * 16 + (l >> 4) * 4 + r;
        const int n = n0 + wn * 64 + j * 16 + (l & 15);
        out[(size_t)m * DD + n] = f2bf(acc[i][j][r]);
      }
}

// ---- kernel 2: Scb = bf16(Q K^T / 32), 128x256 tiles, lower-tri only.
//      tcode 0..71 -> (mb, nb): tiles per mb = mb/2 + 1. ----
__global__ __launch_bounds__(256, 2) void scores_gemm(const u16* __restrict__ Q,
                                                      const u16* __restrict__ Kt,
                                                      u16* __restrict__ Scb) {
  const int b = blockIdx.y;
  const int tcode = blockIdx.x;  // 0..71
  int mb = 0, c = 0;
  while (c + (mb >> 1) + 1 <= tcode) { c += (mb >> 1) + 1; ++mb; }
  const int nb = tcode - c;
  const int m0 = mb * 128, n0 = nb * 256;

  floatx4 acc[4][8];
  gemm_core_128x256(Q + (size_t)b * SS * DD, Kt + (size_t)b * SS * DD, DD, DD, m0, n0, DD, acc);

  u16* out = Scb + (size_t)b * SS * SS;
  const int t = threadIdx.x, w = t >> 6, l = t & 63;
  const int wm = w >> 1, wn = w & 1;
#pragma unroll
  for (int i = 0; i < 4; ++i)
#pragma unroll
    for (int j = 0; j < 8; ++j)
#pragma unroll
      for (int r = 0; r < 4; ++r) {
        const int m = m0 + wm * 64 + i * 16 + (l >> 4) * 4 + r;
        const int n = n0 + wn * 128 + j * 16 + (l & 15);
        out[(size_t)m * SS + n] = f2bf(acc[i][j][r] * 0.03125f);  // 1/sqrt(1024)
      }
}

// ---- kernel 3: causal row softmax (bf16 in/out, one wave per row) +
//      zero-init of out rows >=1024 (pv atomic-combine region). ----
__global__ __launch_bounds__(256) void softmax_causal(const u16* __restrict__ Scb,
                                                      u16* __restrict__ P,
                                                      float* __restrict__ outz) {
  {  // zero out[b][1024..2047][*]: 1M float4 over 524288 threads, 2 each
    float4* ov = (float4*)outz;
    const int tid = blockIdx.x * 256 + threadIdx.x;
#pragma unroll
    for (int rep = 0; rep < 2; ++rep) {
      const int z = tid * 2 + rep;               // 0..1048575
      const int b = z >> 18, local = z & 262143;
      ov[(size_t)b * 524288 + 262144 + local] = (float4){0.f, 0.f, 0.f, 0.f};
    }
  }

  const int row = blockIdx.x * 4 + (threadIdx.x >> 6);  // b*2048 + i
  const int l = threadIdx.x & 63;
  const int b = row >> 11, i = row & 2047;
  const u16* s = Scb + (size_t)b * SS * SS + (size_t)i * SS;
  u16* p = P + (size_t)b * SS * SS + (size_t)i * SS;
  const int n = i + 1;
  const int jend = (i + 128) & ~127;
  const int nc = (jend + 511) >> 9;

  float v[4][8];
  float mx = -INFINITY;
#pragma unroll
  for (int c = 0; c < 4; ++c) {
    if (c < nc) {
      const int col = c * 512 + l * 8;
      uint4 raw = *(const uint4*)(s + col);
      v[c][0] = bflo2f(raw.x); v[c][1] = bfhi2f(raw.x);
      v[c][2] = bflo2f(raw.y); v[c][3] = bfhi2f(raw.y);
      v[c][4] = bflo2f(raw.z); v[c][5] = bfhi2f(raw.z);
      v[c][6] = bflo2f(raw.w); v[c][7] = bfhi2f(raw.w);
#pragma unroll
      for (int e = 0; e < 8; ++e) {
        v[c][e] = (col + e < n) ? v[c][e] : -INFINITY;
        mx = fmaxf(mx, v[c][e]);
      }
    }
  }
#pragma unroll
  for (int o = 32; o > 0; o >>= 1) mx = fmaxf(mx, __shfl_xor(mx, o, 64));

  float sum = 0.f;
#pragma unroll
  for (int c = 0; c < 4; ++c) {
    if (c < nc) {
#pragma unroll
      for (int e = 0; e < 8; ++e) {
        v[c][e] = __expf(v[c][e] - mx);
        sum += v[c][e];
      }
    }
  }
#pragma unroll
  for (int o = 32; o > 0; o >>= 1) sum += __shfl_xor(sum, o, 64);
  const float inv = 1.0f / sum;

#pragma unroll
  for (int c = 0; c < 4; ++c) {
    if (c < nc) {
      const int col = c * 512 + l * 8;
      if (col < jend) {
        uint4 o4;
        o4.x = (uint32_t)f2bf(v[c][0] * inv) | ((uint32_t)f2bf(v[c][1] * inv) << 16);
        o4.y = (uint32_t)f2bf(v[c][2] * inv) | ((uint32_t)f2bf(v[c][3] * inv) << 16);
        o4.z = (uint32_t)f2bf(v[c][4] * inv) | ((uint32_t)f2bf(v[c][5] * inv) << 16);
        o4.w = (uint32_t)f2bf(v[c][6] * inv) | ((uint32_t)f2bf(v[c][7] * inv) << 16);
        *(uint4*)(p + col) = o4;
      }
    }
  }
}

// ---- kernel 4: O = P V, K-split jobs <=1024 units, longest-first (z slowest).
//      mb<8: single job, plain store. mb>=8: two jobs, atomicAdd (out zeroed). ----
__device__ const int jb_mb[24] = {  7,  8,  9, 10, 11, 12, 13, 14, 15, 15,
                                    6, 14,  5, 13,  4, 12,  3, 11,  2, 10,
                                    1,  9,  0,  8 };
__device__ const int jb_k0[24] = {  0,  0,  0,  0,  0,  0,  0,  0,  0, 1024,
                                    0, 1024, 0, 1024, 0, 1024, 0, 1024, 0, 1024,
                                    0, 1024, 0, 1024 };
__device__ const int jb_k1[24] = { 1024, 1024, 1024, 1024, 1024, 1024, 1024, 1024, 1024, 2048,
                                   896, 1920, 768, 1792, 640, 1664, 512, 1536, 384, 1408,
                                   256, 1280, 128, 1152 };

__global__ __launch_bounds__(256, 2) void pv_gemm(const u16* __restrict__ P,
                                                  const u16* __restrict__ Vt,
                                                  float* __restrict__ out) {
  const int b = blockIdx.y;
  const int job = blockIdx.z;
  const int mb = jb_mb[job];
  const int k0 = jb_k0[job], k1 = jb_k1[job];
  const int m0 = mb * 128, n0 = blockIdx.x * 128;

  floatx4 acc[4][4];
  gemm_core_128(P + (size_t)b * SS * SS + k0,
                Vt + (size_t)b * DD * SS + k0,
                SS, SS, m0, n0, k1 - k0, acc);

  float* o = out + (size_t)b * SS * DD;
  const int t = threadIdx.x, w = t >> 6, l = t & 63;
  const int wm = w >> 1, wn = w & 1;
  const bool single = (mb < 8);
#pragma unroll
  for (int i = 0; i < 4; ++i)
#pragma unroll
    for (int j = 0; j < 4; ++j)
#pragma unroll
      for (int r = 0; r < 4; ++r) {
        const int m = m0 + wm * 64 + i * 16 + (l >> 4) * 4 + r;
        const int n = n0 + wn * 64 + j * 16 + (l & 15);
        if (single) o[(size_t)m * DD + n] = acc[i][j][r];
        else        atomicAdd(&o[(size_t)m * DD + n], acc[i][j][r]);
      }
}

extern "C" void kernel_launch(void* const* d_in, const int* in_sizes, int n_in,
                              void* d_out, int out_size, void* d_ws, size_t ws_size,
                              hipStream_t stream) {
  const float* x  = (const float*)d_in[0];
  const float* WQ = (const float*)d_in[1];
  const float* WK = (const float*)d_in[2];
  const float* WV = (const float*)d_in[3];
  float* out = (float*)d_out;

  // workspace carve (bytes): Wt 6M | xb 16M | Q 16M | K 16M | Vt 16M | P 32M | Scb 32M
  char* ws = (char*)d_ws;
  const size_t WT_OFF = 0;
  const size_t XB_OFF = WT_OFF + (size_t)3072 * 1024 * 2;
  const size_t Q_OFF  = XB_OFF + (size_t)BB * SS * DD * 2;
  const size_t K_OFF  = Q_OFF + (size_t)BB * SS * DD * 2;
  const size_t VT_OFF = K_OFF + (size_t)BB * SS * DD * 2;
  const size_t P_OFF  = VT_OFF + (size_t)BB * SS * DD * 2;
  const size_t SC_OFF = P_OFF + (size_t)BB * SS * SS * 2;
  u16* Wt  = (u16*)(ws + WT_OFF);
  u16* xb  = (u16*)(ws + XB_OFF);
  u16* Q   = (u16*)(ws + Q_OFF);
  u16* Kb  = (u16*)(ws + K_OFF);
  u16* Vt  = (u16*)(ws + VT_OFF);
  u16* P   = (u16*)(ws + P_OFF);
  u16* Scb = (u16*)(ws + SC_OFF);

  hipLaunchKernelGGL(prep, dim3(8960), dim3(256), 0, stream, x, WQ, WK, WV, xb, Wt);
  hipLaunchKernelGGL(qkv_gemm, dim3(64, 24), dim3(256), 0, stream, xb, Wt, Q, Kb, Vt);
  hipLaunchKernelGGL(scores_gemm, dim3(72, 4), dim3(256), 0, stream, Q, Kb, Scb);
  hipLaunchKernelGGL(softmax_causal, dim3(2048), dim3(256), 0, stream, Scb, P, out);
  hipLaunchKernelGGL(pv_gemm, dim3(8, 4, 24), dim3(256), 0, stream, P, Vt, out);
}